// Round 12
// baseline (191.480 us; speedup 1.0000x reference)
//
#include <hip/hip_runtime.h>
#include <cstdint>
#include <cstddef>

// CapsuleLayer dynamic routing, MI355X — R12.
// R11 (direct-from-global Wt fragments, no LDS W staging) +
//  (1) 256-thr / 4-wave blocks: btl moved to grid (grid 1024) -> psm barrier
//      syncs 4 waves instead of 16; ~3-4 blocks/CU interleave on the CU;
//  (2) register double-buffer: next pair's W fragments + x issued before this
//      pair's compute (statically indexed ping-pong, fully unrolled p-loop);
//  (3) no launch_bounds occupancy cap (R10 lesson: ",4" capped VGPR at 64 ->
//      cross-barrier arrays spilled to scratch).
// ws: Wt 33,554,432 B | SP 33,554,432 B | v0 262,144 B | v01 262,144 B.

#define CN     2048
#define JN     32
#define UN     16
#define IN_    16
#define CPB    16
#define PAIRS  (CPB/2)
#define NCHUNK (CN/CPB)      // 128
#define NBG    2             // b-groups of 64

typedef _Float16 f16;
typedef _Float16 f16x2 __attribute__((ext_vector_type(2)));
typedef _Float16 f16x4 __attribute__((ext_vector_type(4)));
typedef _Float16 f16x8 __attribute__((ext_vector_type(8)));
typedef __fp16   h16x2 __attribute__((ext_vector_type(2)));
typedef float    f32x4 __attribute__((ext_vector_type(4)));

static __device__ __forceinline__ f16x2 pkrtz(float a, float b) {
    h16x2 r = __builtin_amdgcn_cvt_pkrtz(a, b);
    return __builtin_bit_cast(f16x2, r);
}
static __device__ __forceinline__ float fdot2(f16x2 a, f16x2 b, float c) {
    return __builtin_amdgcn_fdot2(__builtin_bit_cast(h16x2, a),
                                  __builtin_bit_cast(h16x2, b), c, false);
}
struct P2 { f16x2 a, b; };
static __device__ __forceinline__ f16x4 join2(f16x2 a, f16x2 b) {
    P2 p{a, b};
    return __builtin_bit_cast(f16x4, p);
}
struct P4 { f16x4 a, b; };
static __device__ __forceinline__ f16x8 join4(f16x4 a, f16x4 b) {
    P4 p{a, b};
    return __builtin_bit_cast(f16x8, p);
}
static __device__ __forceinline__ f16x8 pk8(const float* w) {
    return join4(join2(pkrtz(w[0],w[1]), pkrtz(w[2],w[3])),
                 join2(pkrtz(w[4],w[5]), pkrtz(w[6],w[7])));
}

// W f32 [c][j][i][u] -> Wt f16 [c][j][u][i]. 2048 blocks x 256 thr.
__global__ __launch_bounds__(256)
void transpose_W(const float* __restrict__ W, f16* __restrict__ Wt)
{
    const int c = blockIdx.x;
    const int t = threadIdx.x;
#pragma unroll
    for (int h = 0; h < 2; ++h) {
        const int s = t + h*256;          // 0..511
        const int j = s >> 4;
        const int u = s & 15;
        const float* src = W + (size_t)c*8192 + j*256 + u;
        float wv[16];
#pragma unroll
        for (int i = 0; i < 16; ++i) wv[i] = src[i*16];
        f16* dst = Wt + (size_t)c*8192 + j*256 + u*16;
        *(f16x8*)dst       = pk8(wv);
        *(f16x8*)(dst + 8) = pk8(wv + 8);
    }
}

template<int ROUTED>
__global__ __launch_bounds__(256)
void route_kernel(const float* __restrict__ x, const f16* __restrict__ Wt,
                  const float* __restrict__ v01g, float* __restrict__ SP)
{
    __shared__ float psm[2*4*16];     // [cc 2][jq 4][b 16]

    const int tid = threadIdx.x;
    const int l   = tid & 63;
    const int jq  = tid >> 6;     // 4 waves = 4 j-quarters
    const int g   = l >> 4;
    const int m15 = l & 15;

    const int bid   = blockIdx.x;
    const int btl   = bid & 3;            // b-tile (16 b)
    const int bg    = (bid >> 2) & 1;     // b-group of 64
    const int chunk = bid >> 3;           // c-chunk
    const int bl    = btl*16 + m15;
    const int bglob = bg*64 + bl;
    const int cbase = chunk * CPB;
    const int jbase = jq * 8;
    const int ccme  = g >> 1;     // lane's c within the pair (K=32 packing)

    // v01 -> registers (c-invariant)
    f16x2 vfr[8][2];
    if (ROUTED) {
#pragma unroll
        for (int jj = 0; jj < 8; ++jj) {
            f32x4 vv = *(const f32x4*)(v01g + (size_t)bglob*512 + (jbase+jj)*16 + 4*g);
            vfr[jj][0] = pkrtz(vv[0], vv[1]);
            vfr[jj][1] = pkrtz(vv[2], vv[3]);
        }
    }

    f32x4 acc[8];
#pragma unroll
    for (int jj = 0; jj < 8; ++jj) acc[jj] = (f32x4){0.f,0.f,0.f,0.f};
    const f32x4 zero4 = {0.f,0.f,0.f,0.f};

    // ---- register double-buffer: fragments + x for the current/next pair ----
    f16x8 wfr[2][8];
    f16x8 xqp[2];
    {
        const float* xp = x + ((size_t)bglob*CN + (cbase + ccme))*IN_ + (g&1)*8;
        f32x4 a = *(const f32x4*)xp, b = *(const f32x4*)(xp + 4);
        float x8[8] = {a[0],a[1],a[2],a[3],b[0],b[1],b[2],b[3]};
        xqp[0] = pk8(x8);
        const f16* wb = Wt + (size_t)(cbase + ccme)*8192 + jbase*256
                        + m15*16 + (g&1)*8;
#pragma unroll
        for (int jj = 0; jj < 8; ++jj)
            wfr[0][jj] = *(const f16x8*)(wb + jj*256);
    }

#pragma unroll
    for (int p = 0; p < PAIRS; ++p) {
        const int cur = p & 1, nxt = cur ^ 1;   // static after full unroll

        // ---- issue next pair's loads early (hide L2/L3 latency under A+B) ----
        if (p + 1 < PAIRS) {
            const int c0n = cbase + 2*(p+1);
            const float* xp = x + ((size_t)bglob*CN + (c0n + ccme))*IN_ + (g&1)*8;
            f32x4 a = *(const f32x4*)xp, b = *(const f32x4*)(xp + 4);
            float x8[8] = {a[0],a[1],a[2],a[3],b[0],b[1],b[2],b[3]};
            xqp[nxt] = pk8(x8);
            const f16* wb = Wt + (size_t)(c0n + ccme)*8192 + jbase*256
                            + m15*16 + (g&1)*8;
#pragma unroll
            for (int jj = 0; jj < 8; ++jj)
                wfr[nxt][jj] = *(const f16x8*)(wb + jj*256);
        }

        const f16x8 xq = xqp[cur];

        float lme[8];
        float myrden = 0.f;
        if (ROUTED) {
            f16x8 xz;
#pragma unroll
            for (int r = 0; r < 8; ++r) xz[r] = (f16)0.f;
            const f16x8 xb0 = (ccme == 0) ? xq : xz;
            const f16x8 xb1 = (ccme == 0) ? xz : xq;

            float summe = 0.f;
#pragma unroll
            for (int jj = 0; jj < 8; ++jj) {
                f32x4 uh0 = __builtin_amdgcn_mfma_f32_16x16x32_f16(wfr[cur][jj], xb0, zero4, 0,0,0);
                float d0 = fdot2(pkrtz(uh0[0], uh0[1]), vfr[jj][0], 0.f);
                d0       = fdot2(pkrtz(uh0[2], uh0[3]), vfr[jj][1], d0);
                f32x4 uh1 = __builtin_amdgcn_mfma_f32_16x16x32_f16(wfr[cur][jj], xb1, zero4, 0,0,0);
                float d1 = fdot2(pkrtz(uh1[0], uh1[1]), vfr[jj][0], 0.f);
                d1       = fdot2(pkrtz(uh1[2], uh1[3]), vfr[jj][1], d1);
                float t0 = d0 + __shfl_xor(d0, 16);
                float t1 = d1 + __shfl_xor(d1, 16);
                float sown = (ccme == 0) ? t0 : t1;
                float soth = (ccme == 0) ? t1 : t0;
                float dme  = sown + __shfl_xor(soth, 32);
                float e = __expf(dme);            // no max-sub: |logit| << 88
                summe += e;
                lme[jj] = e;
            }
            if ((l & 31) < 16)
                psm[(ccme*4 + jq)*16 + m15] = summe;
            __syncthreads();                      // psm ready (4 waves only)
            {
                const float* pp = psm + ccme*64 + m15;
                myrden = 1.f / (pp[0] + pp[16] + pp[32] + pp[48]);
            }
            __syncthreads();                      // psm consumed
        }

        // ---- phase B: s_j += c_ij * u_hat (c-pair packed K=32) ----
#pragma unroll
        for (int jj = 0; jj < 8; ++jj) {
            f16x8 bx = xq;
            if (ROUTED) {
                const f16 hsc = (f16)(lme[jj] * myrden);
#pragma unroll
                for (int r = 0; r < 8; ++r) bx[r] = xq[r] * hsc;   // v_pk_mul_f16
            }
            acc[jj] = __builtin_amdgcn_mfma_f32_16x16x32_f16(wfr[cur][jj], bx, acc[jj], 0,0,0);
        }
    }

    // partial s: SP[(bg*128+chunk)*64 + bl][j 32][u 16] f32
    float* dst = SP + (((size_t)(bg*NCHUNK + chunk))*64 + bl)*512;
#pragma unroll
    for (int jj = 0; jj < 8; ++jj)
        *(f32x4*)(dst + (jbase+jj)*16 + 4*g) = acc[jj];
}

// Reduce 128 chunk-partials, squash over J. grid 128 (b), block 512 (tid=j*16+u).
__global__ __launch_bounds__(512)
void squash_kernel(const float* __restrict__ SP, float* __restrict__ v0buf,
                   float* __restrict__ v01buf, float* __restrict__ outp, int mode)
{
    __shared__ float sq[512];
    __shared__ float msqs[16];
    const int tid = threadIdx.x;      // j*16 + u
    const int b   = blockIdx.x;
    const int bg  = b >> 6, blb = b & 63;

    const float* base = SP + ((size_t)bg*NCHUNK*64 + blb)*512 + tid;
    float sum = 0.f;
#pragma unroll 8
    for (int ch = 0; ch < NCHUNK; ++ch) sum += base[(size_t)ch * 64 * 512];
    float s = (mode == 0) ? sum * (1.f/32.f) : sum;   // iter0: c_ij = 1/32 exactly

    sq[tid] = s * s;
    __syncthreads();
    if (tid < 16) {
        float m = 0.f;
#pragma unroll
        for (int j2 = 0; j2 < 32; ++j2) m += sq[j2*16 + tid];
        msqs[tid] = m;
    }
    __syncthreads();
    const float msq = msqs[tid & 15];
    const float mag = sqrtf(msq + 1e-8f);
    const float v   = (msq / (1.f + msq)) * (s / (mag + 1e-8f));
    const size_t idx = (size_t)b*512 + tid;
    if (mode == 0)      { v0buf[idx] = v; v01buf[idx] = v; }
    else if (mode == 1) { v01buf[idx] = v0buf[idx] + v; }   // b2 uses v0+v1
    else                { outp[idx] = v; }
}

extern "C" void kernel_launch(void* const* d_in, const int* in_sizes, int n_in,
                              void* d_out, int out_size, void* d_ws, size_t ws_size,
                              hipStream_t stream)
{
    const float* x = (const float*)d_in[0];
    const float* W = (const float*)d_in[1];

    // ws: Wt (32 MiB f16) | SP (32 MiB f32) | v0 | v01
    f16*   Wt  = (f16*)d_ws;
    float* SP  = (float*)((char*)d_ws + (size_t)33554432);
    float* v0  = (float*)((char*)d_ws + (size_t)33554432 * 2);
    float* v01 = v0 + 65536;
    float* out = (float*)d_out;

    transpose_W<<<2048, 256, 0, stream>>>(W, Wt);

    dim3 grid(1024), blk(256);
    route_kernel<0><<<grid, blk, 0, stream>>>(x, Wt, nullptr, SP);
    squash_kernel  <<<128, 512, 0, stream>>>(SP, v0, v01, out, 0);
    route_kernel<1><<<grid, blk, 0, stream>>>(x, Wt, v01, SP);
    squash_kernel  <<<128, 512, 0, stream>>>(SP, v0, v01, out, 1);
    route_kernel<1><<<grid, blk, 0, stream>>>(x, Wt, v01, SP);
    squash_kernel  <<<128, 512, 0, stream>>>(SP, v0, v01, out, 2);
}

// Round 13
// 149.091 us; speedup vs baseline: 1.2843x; 1.2843x over previous
//
#include <hip/hip_runtime.h>
#include <cstdint>
#include <cstddef>

// CapsuleLayer dynamic routing, MI355X — R13.
// R12 (direct-global Wt fragments, 4-wave blocks, register double-buffer) +
// chunk->XCD swizzle: all 8 blocks (2bg x 4btl) of a c-chunk get bid == chunk
// (mod 8) -> same XCD under round-robin dispatch -> chunk's Wt slice (256 KB)
// is fetched once per XCD L2 instead of 8x across XCDs (R12's 3.4x FETCH blowup).
// ws: Wt 33,554,432 B | SP 33,554,432 B | v0 262,144 B | v01 262,144 B.

#define CN     2048
#define JN     32
#define UN     16
#define IN_    16
#define CPB    16
#define PAIRS  (CPB/2)
#define NCHUNK (CN/CPB)      // 128
#define NBG    2             // b-groups of 64

typedef _Float16 f16;
typedef _Float16 f16x2 __attribute__((ext_vector_type(2)));
typedef _Float16 f16x4 __attribute__((ext_vector_type(4)));
typedef _Float16 f16x8 __attribute__((ext_vector_type(8)));
typedef __fp16   h16x2 __attribute__((ext_vector_type(2)));
typedef float    f32x4 __attribute__((ext_vector_type(4)));

static __device__ __forceinline__ f16x2 pkrtz(float a, float b) {
    h16x2 r = __builtin_amdgcn_cvt_pkrtz(a, b);
    return __builtin_bit_cast(f16x2, r);
}
static __device__ __forceinline__ float fdot2(f16x2 a, f16x2 b, float c) {
    return __builtin_amdgcn_fdot2(__builtin_bit_cast(h16x2, a),
                                  __builtin_bit_cast(h16x2, b), c, false);
}
struct P2 { f16x2 a, b; };
static __device__ __forceinline__ f16x4 join2(f16x2 a, f16x2 b) {
    P2 p{a, b};
    return __builtin_bit_cast(f16x4, p);
}
struct P4 { f16x4 a, b; };
static __device__ __forceinline__ f16x8 join4(f16x4 a, f16x4 b) {
    P4 p{a, b};
    return __builtin_bit_cast(f16x8, p);
}
static __device__ __forceinline__ f16x8 pk8(const float* w) {
    return join4(join2(pkrtz(w[0],w[1]), pkrtz(w[2],w[3])),
                 join2(pkrtz(w[4],w[5]), pkrtz(w[6],w[7])));
}

// W f32 [c][j][i][u] -> Wt f16 [c][j][u][i]. 2048 blocks x 256 thr.
__global__ __launch_bounds__(256)
void transpose_W(const float* __restrict__ W, f16* __restrict__ Wt)
{
    const int c = blockIdx.x;
    const int t = threadIdx.x;
#pragma unroll
    for (int h = 0; h < 2; ++h) {
        const int s = t + h*256;          // 0..511
        const int j = s >> 4;
        const int u = s & 15;
        const float* src = W + (size_t)c*8192 + j*256 + u;
        float wv[16];
#pragma unroll
        for (int i = 0; i < 16; ++i) wv[i] = src[i*16];
        f16* dst = Wt + (size_t)c*8192 + j*256 + u*16;
        *(f16x8*)dst       = pk8(wv);
        *(f16x8*)(dst + 8) = pk8(wv + 8);
    }
}

template<int ROUTED>
__global__ __launch_bounds__(256)
void route_kernel(const float* __restrict__ x, const f16* __restrict__ Wt,
                  const float* __restrict__ v01g, float* __restrict__ SP)
{
    __shared__ float psm[2*4*16];     // [cc 2][jq 4][b 16]

    const int tid = threadIdx.x;
    const int l   = tid & 63;
    const int jq  = tid >> 6;     // 4 waves = 4 j-quarters
    const int g   = l >> 4;
    const int m15 = l & 15;

    // chunk->XCD swizzle: all 8 blocks of a chunk share bid mod 8
    const int bid   = blockIdx.x;
    const int xcd   = bid & 7;
    const int k     = bid >> 3;           // 0..127
    const int chunk = (k >> 3) * 8 + xcd; // 0..127
    const int idx   = k & 7;
    const int bg    = idx >> 2;           // b-group of 64
    const int btl   = idx & 3;            // b-tile (16 b)

    const int bl    = btl*16 + m15;
    const int bglob = bg*64 + bl;
    const int cbase = chunk * CPB;
    const int jbase = jq * 8;
    const int ccme  = g >> 1;     // lane's c within the pair (K=32 packing)

    // v01 -> registers (c-invariant)
    f16x2 vfr[8][2];
    if (ROUTED) {
#pragma unroll
        for (int jj = 0; jj < 8; ++jj) {
            f32x4 vv = *(const f32x4*)(v01g + (size_t)bglob*512 + (jbase+jj)*16 + 4*g);
            vfr[jj][0] = pkrtz(vv[0], vv[1]);
            vfr[jj][1] = pkrtz(vv[2], vv[3]);
        }
    }

    f32x4 acc[8];
#pragma unroll
    for (int jj = 0; jj < 8; ++jj) acc[jj] = (f32x4){0.f,0.f,0.f,0.f};
    const f32x4 zero4 = {0.f,0.f,0.f,0.f};

    // ---- register double-buffer: fragments + x for the current/next pair ----
    f16x8 wfr[2][8];
    f16x8 xqp[2];
    {
        const float* xp = x + ((size_t)bglob*CN + (cbase + ccme))*IN_ + (g&1)*8;
        f32x4 a = *(const f32x4*)xp, b = *(const f32x4*)(xp + 4);
        float x8[8] = {a[0],a[1],a[2],a[3],b[0],b[1],b[2],b[3]};
        xqp[0] = pk8(x8);
        const f16* wb = Wt + (size_t)(cbase + ccme)*8192 + jbase*256
                        + m15*16 + (g&1)*8;
#pragma unroll
        for (int jj = 0; jj < 8; ++jj)
            wfr[0][jj] = *(const f16x8*)(wb + jj*256);
    }

#pragma unroll
    for (int p = 0; p < PAIRS; ++p) {
        const int cur = p & 1, nxt = cur ^ 1;   // static after full unroll

        // ---- issue next pair's loads early (hide L2 latency under A+B) ----
        if (p + 1 < PAIRS) {
            const int c0n = cbase + 2*(p+1);
            const float* xp = x + ((size_t)bglob*CN + (c0n + ccme))*IN_ + (g&1)*8;
            f32x4 a = *(const f32x4*)xp, b = *(const f32x4*)(xp + 4);
            float x8[8] = {a[0],a[1],a[2],a[3],b[0],b[1],b[2],b[3]};
            xqp[nxt] = pk8(x8);
            const f16* wb = Wt + (size_t)(c0n + ccme)*8192 + jbase*256
                            + m15*16 + (g&1)*8;
#pragma unroll
            for (int jj = 0; jj < 8; ++jj)
                wfr[nxt][jj] = *(const f16x8*)(wb + jj*256);
        }

        const f16x8 xq = xqp[cur];

        float lme[8];
        float myrden = 0.f;
        if (ROUTED) {
            f16x8 xz;
#pragma unroll
            for (int r = 0; r < 8; ++r) xz[r] = (f16)0.f;
            const f16x8 xb0 = (ccme == 0) ? xq : xz;
            const f16x8 xb1 = (ccme == 0) ? xz : xq;

            float summe = 0.f;
#pragma unroll
            for (int jj = 0; jj < 8; ++jj) {
                f32x4 uh0 = __builtin_amdgcn_mfma_f32_16x16x32_f16(wfr[cur][jj], xb0, zero4, 0,0,0);
                float d0 = fdot2(pkrtz(uh0[0], uh0[1]), vfr[jj][0], 0.f);
                d0       = fdot2(pkrtz(uh0[2], uh0[3]), vfr[jj][1], d0);
                f32x4 uh1 = __builtin_amdgcn_mfma_f32_16x16x32_f16(wfr[cur][jj], xb1, zero4, 0,0,0);
                float d1 = fdot2(pkrtz(uh1[0], uh1[1]), vfr[jj][0], 0.f);
                d1       = fdot2(pkrtz(uh1[2], uh1[3]), vfr[jj][1], d1);
                float t0 = d0 + __shfl_xor(d0, 16);
                float t1 = d1 + __shfl_xor(d1, 16);
                float sown = (ccme == 0) ? t0 : t1;
                float soth = (ccme == 0) ? t1 : t0;
                float dme  = sown + __shfl_xor(soth, 32);
                float e = __expf(dme);            // no max-sub: |logit| << 88
                summe += e;
                lme[jj] = e;
            }
            if ((l & 31) < 16)
                psm[(ccme*4 + jq)*16 + m15] = summe;
            __syncthreads();                      // psm ready (4 waves only)
            {
                const float* pp = psm + ccme*64 + m15;
                myrden = 1.f / (pp[0] + pp[16] + pp[32] + pp[48]);
            }
            __syncthreads();                      // psm consumed
        }

        // ---- phase B: s_j += c_ij * u_hat (c-pair packed K=32) ----
#pragma unroll
        for (int jj = 0; jj < 8; ++jj) {
            f16x8 bx = xq;
            if (ROUTED) {
                const f16 hsc = (f16)(lme[jj] * myrden);
#pragma unroll
                for (int r = 0; r < 8; ++r) bx[r] = xq[r] * hsc;   // v_pk_mul_f16
            }
            acc[jj] = __builtin_amdgcn_mfma_f32_16x16x32_f16(wfr[cur][jj], bx, acc[jj], 0,0,0);
        }
    }

    // partial s: SP[(bg*128+chunk)*64 + bl][j 32][u 16] f32
    float* dst = SP + (((size_t)(bg*NCHUNK + chunk))*64 + bl)*512;
#pragma unroll
    for (int jj = 0; jj < 8; ++jj)
        *(f32x4*)(dst + (jbase+jj)*16 + 4*g) = acc[jj];
}

// Reduce 128 chunk-partials, squash over J. grid 128 (b), block 512 (tid=j*16+u).
__global__ __launch_bounds__(512)
void squash_kernel(const float* __restrict__ SP, float* __restrict__ v0buf,
                   float* __restrict__ v01buf, float* __restrict__ outp, int mode)
{
    __shared__ float sq[512];
    __shared__ float msqs[16];
    const int tid = threadIdx.x;      // j*16 + u
    const int b   = blockIdx.x;
    const int bg  = b >> 6, blb = b & 63;

    const float* base = SP + ((size_t)bg*NCHUNK*64 + blb)*512 + tid;
    float sum = 0.f;
#pragma unroll 8
    for (int ch = 0; ch < NCHUNK; ++ch) sum += base[(size_t)ch * 64 * 512];
    float s = (mode == 0) ? sum * (1.f/32.f) : sum;   // iter0: c_ij = 1/32 exactly

    sq[tid] = s * s;
    __syncthreads();
    if (tid < 16) {
        float m = 0.f;
#pragma unroll
        for (int j2 = 0; j2 < 32; ++j2) m += sq[j2*16 + tid];
        msqs[tid] = m;
    }
    __syncthreads();
    const float msq = msqs[tid & 15];
    const float mag = sqrtf(msq + 1e-8f);
    const float v   = (msq / (1.f + msq)) * (s / (mag + 1e-8f));
    const size_t idx = (size_t)b*512 + tid;
    if (mode == 0)      { v0buf[idx] = v; v01buf[idx] = v; }
    else if (mode == 1) { v01buf[idx] = v0buf[idx] + v; }   // b2 uses v0+v1
    else                { outp[idx] = v; }
}

extern "C" void kernel_launch(void* const* d_in, const int* in_sizes, int n_in,
                              void* d_out, int out_size, void* d_ws, size_t ws_size,
                              hipStream_t stream)
{
    const float* x = (const float*)d_in[0];
    const float* W = (const float*)d_in[1];

    // ws: Wt (32 MiB f16) | SP (32 MiB f32) | v0 | v01
    f16*   Wt  = (f16*)d_ws;
    float* SP  = (float*)((char*)d_ws + (size_t)33554432);
    float* v0  = (float*)((char*)d_ws + (size_t)33554432 * 2);
    float* v01 = v0 + 65536;
    float* out = (float*)d_out;

    transpose_W<<<2048, 256, 0, stream>>>(W, Wt);

    dim3 grid(1024), blk(256);
    route_kernel<0><<<grid, blk, 0, stream>>>(x, Wt, nullptr, SP);
    squash_kernel  <<<128, 512, 0, stream>>>(SP, v0, v01, out, 0);
    route_kernel<1><<<grid, blk, 0, stream>>>(x, Wt, v01, SP);
    squash_kernel  <<<128, 512, 0, stream>>>(SP, v0, v01, out, 1);
    route_kernel<1><<<grid, blk, 0, stream>>>(x, Wt, v01, SP);
    squash_kernel  <<<128, 512, 0, stream>>>(SP, v0, v01, out, 2);
}